// Round 3
// baseline (695.532 us; speedup 1.0000x reference)
//
#include <hip/hip_runtime.h>
#include <cstdint>

// Problem geometry (fixed by the reference)
#define D_IN   4096
#define D_OUT  4096
#define MTOT   16384      // B*S = 8*2048
#define SCALING 2.0f

// GEMM tiling: 256x256 tile, BK=64, 8 waves (2M x 4N), 8-phase pipelined
#define BM 256
#define BN 256
#define BK 64
#define KT (D_IN / BK)    // 64 K-tiles

typedef float  f32x4  __attribute__((ext_vector_type(4)));
typedef __bf16 bf16x8 __attribute__((ext_vector_type(8)));
typedef unsigned short ushort8 __attribute__((ext_vector_type(8)));
typedef int    int4v  __attribute__((ext_vector_type(4)));
typedef float  float4v __attribute__((ext_vector_type(4)));

// round-to-nearest-even f32 -> bf16
__device__ __forceinline__ unsigned short f2bf(float f) {
  union { float f; unsigned u; } v; v.f = f;
  unsigned r = v.u + 0x7FFF + ((v.u >> 16) & 1);
  return (unsigned short)(r >> 16);
}

// async global->LDS, 16B per lane (wave-uniform base + lane*16 on LDS side)
#define ASYNC16(g, l)                                                        \
  __builtin_amdgcn_global_load_lds(                                          \
      (const __attribute__((address_space(1))) unsigned int*)(g),            \
      (__attribute__((address_space(3))) unsigned int*)(l), 16, 0, 0)

#define BAR __builtin_amdgcn_s_barrier()

// ---------------------------------------------------------------- prep: x -> bf16
__global__ __launch_bounds__(256) void prep_x_kernel(const float* __restrict__ x,
                                                     unsigned short* __restrict__ xbf) {
  int i = (blockIdx.x * 256 + threadIdx.x) * 8;
  float4v lo = *(const float4v*)(x + i);
  float4v hi = *(const float4v*)(x + i + 4);
  ushort8 o;
  o[0] = f2bf(lo[0]); o[1] = f2bf(lo[1]); o[2] = f2bf(lo[2]); o[3] = f2bf(lo[3]);
  o[4] = f2bf(hi[0]); o[5] = f2bf(hi[1]); o[6] = f2bf(hi[2]); o[7] = f2bf(hi[3]);
  *(ushort8*)(xbf + i) = o;
}

// ------------------------------------------- prep: W_eff = dequant(codes)+2*delta
__global__ __launch_bounds__(256) void prep_w_kernel(const int* __restrict__ codes,
                                                     const float* __restrict__ scales,
                                                     const float* __restrict__ delta,
                                                     unsigned short* __restrict__ weff) {
  int i = (blockIdx.x * 256 + threadIdx.x) * 8;   // 8 consecutive elems, same group
  int row = i >> 12;          // / D_IN
  int col = i & (D_IN - 1);
  float s = scales[(row << 6) + (col >> 6)];      // 64 groups per row
  int4v   c0 = *(const int4v*)(codes + i);
  int4v   c1 = *(const int4v*)(codes + i + 4);
  float4v d0 = *(const float4v*)(delta + i);
  float4v d1 = *(const float4v*)(delta + i + 4);
  ushort8 o;
  o[0] = f2bf((float)(c0[0] - 8) * s + SCALING * d0[0]);
  o[1] = f2bf((float)(c0[1] - 8) * s + SCALING * d0[1]);
  o[2] = f2bf((float)(c0[2] - 8) * s + SCALING * d0[2]);
  o[3] = f2bf((float)(c0[3] - 8) * s + SCALING * d0[3]);
  o[4] = f2bf((float)(c1[0] - 8) * s + SCALING * d1[0]);
  o[5] = f2bf((float)(c1[1] - 8) * s + SCALING * d1[1]);
  o[6] = f2bf((float)(c1[2] - 8) * s + SCALING * d1[2]);
  o[7] = f2bf((float)(c1[3] - 8) * s + SCALING * d1[3]);
  *(ushort8*)(weff + i) = o;
}

// ---------------------------------------------------------------- main GEMM
// C[M][N] = Xbf[M][K] * Weff[N][K]^T + bias
// 256x256, BK=64, 512 thr (8 waves: wr=wid>>2, wc=wid&3), 8-phase pipelined:
// fragment ds_reads issued ONE PHASE AHEAD; compiler emits counted lgkmcnt
// before each MFMA cluster (only prior-phase reads drained). Counted vmcnt(2)
// at P2 drains tile g+1's staging, leaves B(g+2)h0 in flight (never 0 mid-loop).
//
// LDS slots/buf: [A0 rows0-127][A1][B0][B1], each [128][64] bf16, XOR-swizzled
// byte ^= ((row&7)<<4): inverse-swizzled global source + swizzled ds_read.
// Frag schedule per tile g (buf=g&1):
//   P0: rd b1(4)            | stage A(g+1)h0 | MM(aE,b0,q00)
//   P1: rd aO(8)            | stage A(g+1)h1 | MM(aE,b1,q01)
//   P2: vmcnt(2); rd aE'(8) | stage B(g+2)h0 | MM(aO,b0,q10)
//   P3: rd b0'(4)           | stage B(g+2)h1 | MM(aO,b1,q11)

#define STAGE_A(buf_, kt_, h_) do {                                          \
    char* d_ = &lds[buf_][h_][0] + tid * 16;                                 \
    const unsigned short* s_ = gA + (size_t)(h_) * 128 * D_IN + (kt_) * 64;  \
    ASYNC16(s_, d_);                                                         \
    ASYNC16(s_ + 64 * D_IN, d_ + 8192);                                      \
  } while (0)

#define STAGE_B(buf_, kt_, h_) do {                                          \
    char* d_ = &lds[buf_][2 + (h_)][0] + tid * 16;                           \
    const unsigned short* s_ = gB + (size_t)(h_) * 128 * D_IN + (kt_) * 64;  \
    ASYNC16(s_, d_);                                                         \
    ASYNC16(s_ + 64 * D_IN, d_ + 8192);                                      \
  } while (0)

#define RD_A(buf_, mh_, dst_) do {                                           \
    _Pragma("unroll")                                                        \
    for (int m2 = 0; m2 < 4; ++m2) {                                         \
      const char* p_ = &lds[buf_][wr][0] + ((mh_)*4 + m2) * 2048 + rowb;     \
      dst_[m2][0] = *(const bf16x8*)(p_ + koff0);                            \
      dst_[m2][1] = *(const bf16x8*)(p_ + koff1);                            \
    } } while (0)

#define RD_B(buf_, nh_, dst_) do {                                           \
    _Pragma("unroll")                                                        \
    for (int n2 = 0; n2 < 2; ++n2) {                                         \
      const char* p_ = &lds[buf_][2 + (wc >> 1)][0] + (wc & 1) * 8192 +      \
                       (nh_) * 4096 + n2 * 2048 + rowb;                      \
      dst_[n2][0] = *(const bf16x8*)(p_ + koff0);                            \
      dst_[n2][1] = *(const bf16x8*)(p_ + koff1);                            \
    } } while (0)

#define MM(afr_, bfr_, mh_, nh_) do {                                        \
    __builtin_amdgcn_s_setprio(1);                                           \
    _Pragma("unroll")                                                        \
    for (int m2 = 0; m2 < 4; ++m2) {                                         \
      _Pragma("unroll")                                                      \
      for (int n2 = 0; n2 < 2; ++n2) {                                       \
        acc[(mh_)*4 + m2][(nh_)*2 + n2] = __builtin_amdgcn_mfma_f32_16x16x32_bf16( \
            afr_[m2][0], bfr_[n2][0], acc[(mh_)*4 + m2][(nh_)*2 + n2], 0, 0, 0);   \
        acc[(mh_)*4 + m2][(nh_)*2 + n2] = __builtin_amdgcn_mfma_f32_16x16x32_bf16( \
            afr_[m2][1], bfr_[n2][1], acc[(mh_)*4 + m2][(nh_)*2 + n2], 0, 0, 0);   \
      } }                                                                    \
    __builtin_amdgcn_s_setprio(0);                                           \
  } while (0)

// One K-tile: buf_ is a LITERAL 0/1; SA_/SB_/PRE_ compile-time guards;
// VMTOK_ is the vmcnt immediate as a string ("2" steady, "0" drain).
#define KTILE(buf_, g_, SA_, SB_, VMTOK_, PRE_) do {                         \
    /* P0 */                                                                 \
    RD_B(buf_, 1, b1);                                                       \
    if (SA_) STAGE_A(1 - (buf_), (g_) + 1, 0);                               \
    BAR;                                                                     \
    MM(aE, b0, 0, 0);                                                        \
    BAR;                                                                     \
    /* P1 */                                                                 \
    RD_A(buf_, 1, aO);                                                       \
    if (SA_) STAGE_A(1 - (buf_), (g_) + 1, 1);                               \
    BAR;                                                                     \
    MM(aE, b1, 0, 1);                                                        \
    BAR;                                                                     \
    /* P2 */                                                                 \
    if (SB_) STAGE_B(buf_, (g_) + 2, 0);                                     \
    asm volatile("s_waitcnt vmcnt(" VMTOK_ ")" ::: "memory");                \
    if (PRE_) RD_A(1 - (buf_), 0, aE);                                       \
    BAR;                                                                     \
    MM(aO, b0, 1, 0);                                                        \
    BAR;                                                                     \
    /* P3 */                                                                 \
    if (PRE_) RD_B(1 - (buf_), 0, b0);                                       \
    if (SB_) STAGE_B(buf_, (g_) + 2, 1);                                     \
    BAR;                                                                     \
    MM(aO, b1, 1, 1);                                                        \
    BAR;                                                                     \
  } while (0)

__global__ __launch_bounds__(512, 2) void gemm8_kernel(const unsigned short* __restrict__ xbf,
                                                       const unsigned short* __restrict__ weff,
                                                       const float* __restrict__ bias,
                                                       float* __restrict__ out) {
  __shared__ __attribute__((aligned(1024))) char lds[2][4][16384];  // 128 KiB

  const int tid  = threadIdx.x;
  const int lane = tid & 63;
  const int wid  = tid >> 6;
  const int wr   = wid >> 2;        // 0..1  (M half)
  const int wc   = wid & 3;         // 0..3  (N quarter)

  // bijective XCD swizzle: 1024 wgs, 8 XCDs -> each XCD gets 8 M-rows x 16 N-cols
  const int id  = blockIdx.x;
  const int nid = (id & 7) * 128 + (id >> 3);
  const int tn  = nid & 15;         // N tile (16)
  const int tm  = nid >> 4;         // M tile (64)

  // ds_read lane offsets (swizzled): addr = row*128 + ((kk*64 + (l>>4)*16) ^ ((l&7)<<4))
  const int rowb  = (lane & 15) * 128;
  const int kx    = (lane & 7) << 4;
  const int koff0 = (((lane >> 4) * 16) ^ kx);
  const int koff1 = ((64 + (lane >> 4) * 16) ^ kx);

  // staging lane offsets (inverse-swizzled source)
  const int sr = tid >> 3;                        // row within 64-row chunk
  const int ke = ((tid & 7) ^ (sr & 7)) * 8;      // permuted k-element offset
  const unsigned short* gA = xbf  + (size_t)(tm * BM + sr) * D_IN + ke;
  const unsigned short* gB = weff + (size_t)(tn * BN + sr) * D_IN + ke;

  const int col0 = tn * BN + wc * 64 + (lane & 15);

  f32x4 acc[8][4] = {};
  bf16x8 aE[4][2], aO[4][2], b0[2][2], b1[2][2];

  // bias preload FIRST so in-loop vmcnt counts stay exact (drained by prologue wait)
  float bv[4];
#pragma unroll
  for (int n = 0; n < 4; ++n) bv[n] = bias[col0 + n * 16];

  // prologue: tile 0 (A+B) -> buf0 ; B of tile 1 -> buf1
  STAGE_A(0, 0, 0); STAGE_A(0, 0, 1);
  STAGE_B(0, 0, 0); STAGE_B(0, 0, 1);
  STAGE_B(1, 1, 0); STAGE_B(1, 1, 1);
  asm volatile("s_waitcnt vmcnt(4)" ::: "memory");  // tile0 + bias landed; B(1) in flight
  BAR;
  RD_A(0, 0, aE); RD_B(0, 0, b0);                   // preload for tile 0 P0

  for (int g = 0; g < KT - 2; g += 2) {
    KTILE(0, g,     1, 1, "2", 1);
    KTILE(1, g + 1, 1, 1, "2", 1);
  }
  KTILE(0, KT - 2, 1, 0, "0", 1);   // stages A(KT-1) only; full drain before preload
  KTILE(1, KT - 1, 0, 0, "0", 0);   // pure compute

  // epilogue: C/D layout col = lane&15, row = (lane>>4)*4 + j  [m89-verified]
  const int row0 = tm * BM + wr * 128 + (lane >> 4) * 4;
#pragma unroll
  for (int n = 0; n < 4; ++n) {
    const int col = col0 + n * 16;
#pragma unroll
    for (int m = 0; m < 8; ++m) {
      const int r = row0 + m * 16;
#pragma unroll
      for (int j = 0; j < 4; ++j)
        out[(size_t)(r + j) * D_OUT + col] = acc[m][n][j] + bv[n];
    }
  }
}

extern "C" void kernel_launch(void* const* d_in, const int* in_sizes, int n_in,
                              void* d_out, int out_size, void* d_ws, size_t ws_size,
                              hipStream_t stream) {
  const float* x      = (const float*)d_in[0];
  const int*   codes  = (const int*)d_in[1];
  const float* scales = (const float*)d_in[2];
  const float* bias   = (const float*)d_in[3];
  const float* delta  = (const float*)d_in[4];
  float* out = (float*)d_out;

  unsigned short* xbf  = (unsigned short*)d_ws;                    // 128 MiB
  unsigned short* weff = xbf + (size_t)MTOT * D_IN;                // +32 MiB

  prep_x_kernel<<<(MTOT * D_IN) / (256 * 8), 256, 0, stream>>>(x, xbf);
  prep_w_kernel<<<(D_OUT * D_IN) / (256 * 8), 256, 0, stream>>>(codes, scales, delta, weff);

  gemm8_kernel<<<(MTOT / BM) * (D_OUT / BN), 512, 0, stream>>>(xbf, weff, bias, out);
}

// Round 4
// 576.165 us; speedup vs baseline: 1.2072x; 1.2072x over previous
//
#include <hip/hip_runtime.h>
#include <cstdint>

// Problem geometry (fixed by the reference)
#define D_IN   4096
#define D_OUT  4096
#define MTOT   16384      // B*S = 8*2048
#define SCALING 2.0f

// GEMM tiling: 256x256 tile, BK=64, 8 waves (2M x 4N), 8-phase schedule
#define BM 256
#define BN 256
#define BK 64
#define KT (D_IN / BK)    // 64 K-tiles

typedef float  f32x4  __attribute__((ext_vector_type(4)));
typedef __bf16 bf16x8 __attribute__((ext_vector_type(8)));
typedef unsigned short ushort8 __attribute__((ext_vector_type(8)));
typedef int    int4v  __attribute__((ext_vector_type(4)));
typedef float  float4v __attribute__((ext_vector_type(4)));

// round-to-nearest-even f32 -> bf16
__device__ __forceinline__ unsigned short f2bf(float f) {
  union { float f; unsigned u; } v; v.f = f;
  unsigned r = v.u + 0x7FFF + ((v.u >> 16) & 1);
  return (unsigned short)(r >> 16);
}

// async global->LDS, 16B per lane (wave-uniform base + lane*16 on LDS side)
#define ASYNC16(g, l)                                                        \
  __builtin_amdgcn_global_load_lds(                                          \
      (const __attribute__((address_space(1))) unsigned int*)(g),            \
      (__attribute__((address_space(3))) unsigned int*)(l), 16, 0, 0)

#define BAR    __builtin_amdgcn_s_barrier()
#define LGKM0  asm volatile("s_waitcnt lgkmcnt(0)" ::: "memory")
#define VMW(n) asm volatile("s_waitcnt vmcnt(" #n ")" ::: "memory")

// ---------------------------------------------------------------- prep: x -> bf16
__global__ __launch_bounds__(256) void prep_x_kernel(const float* __restrict__ x,
                                                     unsigned short* __restrict__ xbf) {
  int i = (blockIdx.x * 256 + threadIdx.x) * 8;
  float4v lo = *(const float4v*)(x + i);
  float4v hi = *(const float4v*)(x + i + 4);
  ushort8 o;
  o[0] = f2bf(lo[0]); o[1] = f2bf(lo[1]); o[2] = f2bf(lo[2]); o[3] = f2bf(lo[3]);
  o[4] = f2bf(hi[0]); o[5] = f2bf(hi[1]); o[6] = f2bf(hi[2]); o[7] = f2bf(hi[3]);
  *(ushort8*)(xbf + i) = o;
}

// ------------------------------------------- prep: W_eff = dequant(codes)+2*delta
__global__ __launch_bounds__(256) void prep_w_kernel(const int* __restrict__ codes,
                                                     const float* __restrict__ scales,
                                                     const float* __restrict__ delta,
                                                     unsigned short* __restrict__ weff) {
  int i = (blockIdx.x * 256 + threadIdx.x) * 8;   // 8 consecutive elems, same group
  int row = i >> 12;          // / D_IN
  int col = i & (D_IN - 1);
  float s = scales[(row << 6) + (col >> 6)];      // 64 groups per row
  int4v   c0 = *(const int4v*)(codes + i);
  int4v   c1 = *(const int4v*)(codes + i + 4);
  float4v d0 = *(const float4v*)(delta + i);
  float4v d1 = *(const float4v*)(delta + i + 4);
  ushort8 o;
  o[0] = f2bf((float)(c0[0] - 8) * s + SCALING * d0[0]);
  o[1] = f2bf((float)(c0[1] - 8) * s + SCALING * d0[1]);
  o[2] = f2bf((float)(c0[2] - 8) * s + SCALING * d0[2]);
  o[3] = f2bf((float)(c0[3] - 8) * s + SCALING * d0[3]);
  o[4] = f2bf((float)(c1[0] - 8) * s + SCALING * d1[0]);
  o[5] = f2bf((float)(c1[1] - 8) * s + SCALING * d1[1]);
  o[6] = f2bf((float)(c1[2] - 8) * s + SCALING * d1[2]);
  o[7] = f2bf((float)(c1[3] - 8) * s + SCALING * d1[3]);
  *(ushort8*)(weff + i) = o;
}

// ---------------------------------------------------------------- main GEMM
// C[M][N] = Xbf[M][K] * Weff[N][K]^T + bias
// 256x256, BK=64, 512 thr (8 waves: wr=wid>>2, wc=wid&3), 8-phase.
// Balanced reads 8/4/8/4: b0 of tile g+1 is read during P3 of tile g
// (b0 frag last used at P2 -> clean WAR; single-buffered frags, 64 VGPR).
// Two counted vmcnts per tile (never 0 mid-loop):
//   P3-start vmcnt(6): queue = B(g+1)x4, A(g+1)x4, B(g+2)h0 x2 (10) -> drains B(g+1)
//   P3-end   vmcnt(4): queue = A(g+1)x4, B(g+2)x4 (8)              -> drains A(g+1)
// LDS slots/buf: [A0 rows0-127][A1][B0][B1], each [128][64] bf16, XOR-swizzled
// byte ^= ((row&7)<<4): inverse-swizzled global source + swizzled ds_read.

#define STAGE_A(buf_, kt_, h_) do {                                          \
    char* d_ = &lds[buf_][h_][0] + tid * 16;                                 \
    const unsigned short* s_ = gA + (size_t)(h_) * 128 * D_IN + (kt_) * 64;  \
    ASYNC16(s_, d_);                                                         \
    ASYNC16(s_ + 64 * D_IN, d_ + 8192);                                      \
  } while (0)

#define STAGE_B(buf_, kt_, h_) do {                                          \
    char* d_ = &lds[buf_][2 + (h_)][0] + tid * 16;                           \
    const unsigned short* s_ = gB + (size_t)(h_) * 128 * D_IN + (kt_) * 64;  \
    ASYNC16(s_, d_);                                                         \
    ASYNC16(s_ + 64 * D_IN, d_ + 8192);                                      \
  } while (0)

#define RD_A(buf_, mh_, dst_) do {                                           \
    _Pragma("unroll")                                                        \
    for (int m2 = 0; m2 < 4; ++m2) {                                         \
      const char* p_ = &lds[buf_][wr][0] + ((mh_)*4 + m2) * 2048 + rowb;     \
      dst_[m2][0] = *(const bf16x8*)(p_ + koff0);                            \
      dst_[m2][1] = *(const bf16x8*)(p_ + koff1);                            \
    } } while (0)

#define RD_B(buf_, nh_, dst_) do {                                           \
    _Pragma("unroll")                                                        \
    for (int n2 = 0; n2 < 2; ++n2) {                                         \
      const char* p_ = &lds[buf_][2 + (wc >> 1)][0] + (wc & 1) * 8192 +      \
                       (nh_) * 4096 + n2 * 2048 + rowb;                      \
      dst_[n2][0] = *(const bf16x8*)(p_ + koff0);                            \
      dst_[n2][1] = *(const bf16x8*)(p_ + koff1);                            \
    } } while (0)

#define MM(afr_, bfr_, mh_, nh_) do {                                        \
    __builtin_amdgcn_s_setprio(1);                                           \
    _Pragma("unroll")                                                        \
    for (int m2 = 0; m2 < 4; ++m2) {                                         \
      _Pragma("unroll")                                                      \
      for (int n2 = 0; n2 < 2; ++n2) {                                       \
        acc[(mh_)*4 + m2][(nh_)*2 + n2] = __builtin_amdgcn_mfma_f32_16x16x32_bf16( \
            afr_[m2][0], bfr_[n2][0], acc[(mh_)*4 + m2][(nh_)*2 + n2], 0, 0, 0);   \
        acc[(mh_)*4 + m2][(nh_)*2 + n2] = __builtin_amdgcn_mfma_f32_16x16x32_bf16( \
            afr_[m2][1], bfr_[n2][1], acc[(mh_)*4 + m2][(nh_)*2 + n2], 0, 0, 0);   \
      } }                                                                    \
    __builtin_amdgcn_s_setprio(0);                                           \
  } while (0)

// One K-tile. SA_/SB_/PRE_ are 0/1 compile-time guards; VMA_/VMB_ are the
// two vmcnt statements (or (void)0).
#define KTILE(buf_, g_, SA_, SB_, PRE_, VMA_, VMB_) do {                     \
    /* P0: MM(a_h0, b0) ; rd a_h0 issued here */                             \
    RD_A(buf_, 0, a);                                                        \
    if (SA_) STAGE_A((buf_) ^ 1, (g_) + 1, 0);                               \
    BAR; LGKM0;                                                              \
    MM(a, b0, 0, 0);                                                         \
    BAR;                                                                     \
    /* P1: MM(a_h0, b1) */                                                   \
    RD_B(buf_, 1, b1);                                                       \
    if (SA_) STAGE_A((buf_) ^ 1, (g_) + 1, 1);                               \
    BAR; LGKM0;                                                              \
    MM(a, b1, 0, 1);                                                         \
    BAR;                                                                     \
    /* P2: MM(a_h1, b0) — last use of b0 */                                  \
    RD_A(buf_, 1, a);                                                        \
    if (SB_) STAGE_B(buf_, (g_) + 2, 0);                                     \
    BAR; LGKM0;                                                              \
    MM(a, b0, 1, 0);                                                         \
    BAR;                                                                     \
    /* P3: MM(a_h1, b1) ; prefetch b0 of tile g+1 inside MFMA region */      \
    VMA_;                                                                    \
    if (SB_) STAGE_B(buf_, (g_) + 2, 1);                                     \
    BAR;                                                                     \
    if (PRE_) RD_B((buf_) ^ 1, 0, b0);                                       \
    MM(a, b1, 1, 1);                                                         \
    VMB_;                                                                    \
    BAR;                                                                     \
  } while (0)

__global__ __launch_bounds__(512, 2) void gemm8_kernel(const unsigned short* __restrict__ xbf,
                                                       const unsigned short* __restrict__ weff,
                                                       const float* __restrict__ bias,
                                                       float* __restrict__ out) {
  __shared__ __attribute__((aligned(1024))) char lds[2][4][16384];  // 128 KiB

  const int tid  = threadIdx.x;
  const int lane = tid & 63;
  const int wid  = tid >> 6;
  const int wr   = wid >> 2;        // 0..1  (M half)
  const int wc   = wid & 3;         // 0..3  (N quarter)

  // bijective XCD swizzle: 1024 wgs, 8 XCDs -> each XCD gets 8 M-rows x 16 N-cols
  const int id  = blockIdx.x;
  const int nid = (id & 7) * 128 + (id >> 3);
  const int tn  = nid & 15;         // N tile (16)
  const int tm  = nid >> 4;         // M tile (64)

  // ds_read lane offsets (swizzled): addr = row*128 + ((kk*64 + (l>>4)*16) ^ ((l&7)<<4))
  const int rowb  = (lane & 15) * 128;
  const int kx    = (lane & 7) << 4;
  const int koff0 = (((lane >> 4) * 16) ^ kx);
  const int koff1 = ((64 + (lane >> 4) * 16) ^ kx);

  // staging lane offsets (inverse-swizzled source)
  const int sr = tid >> 3;                        // row within 64-row chunk
  const int ke = ((tid & 7) ^ (sr & 7)) * 8;      // permuted k-element offset
  const unsigned short* gA = xbf  + (size_t)(tm * BM + sr) * D_IN + ke;
  const unsigned short* gB = weff + (size_t)(tn * BN + sr) * D_IN + ke;

  f32x4 acc[8][4] = {};
  bf16x8 a[4][2], b0[2][2], b1[2][2];

  // prologue: tile 0 (A+B) -> buf0 ; B of tile 1 -> buf1  (12 loads)
  STAGE_A(0, 0, 0); STAGE_A(0, 0, 1);
  STAGE_B(0, 0, 0); STAGE_B(0, 0, 1);
  STAGE_B(1, 1, 0); STAGE_B(1, 1, 1);
  VMW(4);           // tile 0 landed; B(1)x4 stays in flight
  BAR;
  RD_B(0, 0, b0);   // preload b0 for tile 0 (auto lgkm wait at first MM)

  int buf = 0;
  for (int g = 0; g < KT - 2; ++g) {
    KTILE(buf, g, 1, 1, 1, VMW(6), VMW(4));
    buf ^= 1;
  }
  // tail: tile KT-2 (buf 0): stage A(KT-1) only; queue at P3-start = B(KT-1)x4 + A(KT-1)x4
  KTILE(0, KT - 2, 1, 0, 1, VMW(4), VMW(0));
  // tile KT-1 (buf 1): pure compute
  KTILE(1, KT - 1, 0, 0, 0, (void)0, (void)0);

  // epilogue: C/D layout col = lane&15, row = (lane>>4)*4 + j  [m89-verified]
  const int row0 = tm * BM + wr * 128 + (lane >> 4) * 4;
  const int col0 = tn * BN + wc * 64 + (lane & 15);
#pragma unroll
  for (int n = 0; n < 4; ++n) {
    const int col = col0 + n * 16;
    const float bv = bias[col];
#pragma unroll
    for (int m = 0; m < 8; ++m) {
      const int r = row0 + m * 16;
#pragma unroll
      for (int j = 0; j < 4; ++j)
        out[(size_t)(r + j) * D_OUT + col] = acc[m][n][j] + bv;
    }
  }
}

extern "C" void kernel_launch(void* const* d_in, const int* in_sizes, int n_in,
                              void* d_out, int out_size, void* d_ws, size_t ws_size,
                              hipStream_t stream) {
  const float* x      = (const float*)d_in[0];
  const int*   codes  = (const int*)d_in[1];
  const float* scales = (const float*)d_in[2];
  const float* bias   = (const float*)d_in[3];
  const float* delta  = (const float*)d_in[4];
  float* out = (float*)d_out;

  unsigned short* xbf  = (unsigned short*)d_ws;                    // 128 MiB
  unsigned short* weff = xbf + (size_t)MTOT * D_IN;                // +32 MiB

  prep_x_kernel<<<(MTOT * D_IN) / (256 * 8), 256, 0, stream>>>(x, xbf);
  prep_w_kernel<<<(D_OUT * D_IN) / (256 * 8), 256, 0, stream>>>(codes, scales, delta, weff);

  gemm8_kernel<<<(MTOT / BM) * (D_OUT / BN), 512, 0, stream>>>(xbf, weff, bias, out);
}

// Round 5
// 571.532 us; speedup vs baseline: 1.2170x; 1.0081x over previous
//
#include <hip/hip_runtime.h>
#include <cstdint>

// Problem geometry (fixed by the reference)
#define D_IN   4096
#define D_OUT  4096
#define MTOT   16384      // B*S = 8*2048
#define SCALING 2.0f

// GEMM tiling: 256x256 tile, BK=64, 8 waves (2M x 4N), 8-phase schedule
#define BM 256
#define BN 256
#define BK 64
#define KT (D_IN / BK)    // 64 K-tiles

typedef float  f32x4  __attribute__((ext_vector_type(4)));
typedef __bf16 bf16x8 __attribute__((ext_vector_type(8)));
typedef unsigned short ushort8 __attribute__((ext_vector_type(8)));
typedef int    int4v  __attribute__((ext_vector_type(4)));
typedef float  float4v __attribute__((ext_vector_type(4)));

// round-to-nearest-even f32 -> bf16
__device__ __forceinline__ unsigned short f2bf(float f) {
  union { float f; unsigned u; } v; v.f = f;
  unsigned r = v.u + 0x7FFF + ((v.u >> 16) & 1);
  return (unsigned short)(r >> 16);
}

// async global->LDS, 16B per lane (wave-uniform base + lane*16 on LDS side)
#define ASYNC16(g, l)                                                        \
  __builtin_amdgcn_global_load_lds(                                          \
      (const __attribute__((address_space(1))) unsigned int*)(g),            \
      (__attribute__((address_space(3))) unsigned int*)(l), 16, 0, 0)

#define BAR    __builtin_amdgcn_s_barrier()
#define VMW(n) asm volatile("s_waitcnt vmcnt(" #n ")" ::: "memory")

// ---------------------------------------------------------------- prep: x -> bf16
__global__ __launch_bounds__(256) void prep_x_kernel(const float* __restrict__ x,
                                                     unsigned short* __restrict__ xbf) {
  int i = (blockIdx.x * 256 + threadIdx.x) * 8;
  float4v lo = *(const float4v*)(x + i);
  float4v hi = *(const float4v*)(x + i + 4);
  ushort8 o;
  o[0] = f2bf(lo[0]); o[1] = f2bf(lo[1]); o[2] = f2bf(lo[2]); o[3] = f2bf(lo[3]);
  o[4] = f2bf(hi[0]); o[5] = f2bf(hi[1]); o[6] = f2bf(hi[2]); o[7] = f2bf(hi[3]);
  *(ushort8*)(xbf + i) = o;
}

// ------------------------------------------- prep: W_eff = dequant(codes)+2*delta
__global__ __launch_bounds__(256) void prep_w_kernel(const int* __restrict__ codes,
                                                     const float* __restrict__ scales,
                                                     const float* __restrict__ delta,
                                                     unsigned short* __restrict__ weff) {
  int i = (blockIdx.x * 256 + threadIdx.x) * 8;   // 8 consecutive elems, same group
  int row = i >> 12;          // / D_IN
  int col = i & (D_IN - 1);
  float s = scales[(row << 6) + (col >> 6)];      // 64 groups per row
  int4v   c0 = *(const int4v*)(codes + i);
  int4v   c1 = *(const int4v*)(codes + i + 4);
  float4v d0 = *(const float4v*)(delta + i);
  float4v d1 = *(const float4v*)(delta + i + 4);
  ushort8 o;
  o[0] = f2bf((float)(c0[0] - 8) * s + SCALING * d0[0]);
  o[1] = f2bf((float)(c0[1] - 8) * s + SCALING * d0[1]);
  o[2] = f2bf((float)(c0[2] - 8) * s + SCALING * d0[2]);
  o[3] = f2bf((float)(c0[3] - 8) * s + SCALING * d0[3]);
  o[4] = f2bf((float)(c1[0] - 8) * s + SCALING * d1[0]);
  o[5] = f2bf((float)(c1[1] - 8) * s + SCALING * d1[1]);
  o[6] = f2bf((float)(c1[2] - 8) * s + SCALING * d1[2]);
  o[7] = f2bf((float)(c1[3] - 8) * s + SCALING * d1[3]);
  *(ushort8*)(weff + i) = o;
}

// ---------------------------------------------------------------- main GEMM
// C[M][N] = Xbf[M][K] * Weff[N][K]^T + bias
// 256x256, BK=64, 512 thr (8 waves: wr=wid>>2, wc=wid&3), 8-phase.
// Reads balanced 8/4/8/4 (b0 of tile g+1 prefetched in P3 of tile g).
// NO explicit lgkmcnt(0): frags are C++ ds_reads, compiler emits progressive
// counted lgkmcnt before each consuming MFMA -> LDS completion overlaps MFMA.
// Two counted vmcnts per tile (never 0 mid-loop), queue-audited:
//   P3-start vmcnt(6): drains B(g+1)  (prefetch b0 reads that slot)
//   P3-end   vmcnt(4): drains A(g+1)  (next P0 reads it)
// LDS slots/buf: [A0 rows0-127][A1][B0][B1], each [128][64] bf16, XOR-swizzled
// byte ^= ((row&7)<<4): inverse-swizzled global source + swizzled ds_read.
// Main loop unrolled x2 so buf is a LITERAL (immediate-offset folding, no VALU).

#define STAGE_A(buf_, kt_, h_) do {                                          \
    char* d_ = &lds[buf_][h_][0] + tid * 16;                                 \
    const unsigned short* s_ = gA + (size_t)(h_) * 128 * D_IN + (kt_) * 64;  \
    ASYNC16(s_, d_);                                                         \
    ASYNC16(s_ + 64 * D_IN, d_ + 8192);                                      \
  } while (0)

#define STAGE_B(buf_, kt_, h_) do {                                          \
    char* d_ = &lds[buf_][2 + (h_)][0] + tid * 16;                           \
    const unsigned short* s_ = gB + (size_t)(h_) * 128 * D_IN + (kt_) * 64;  \
    ASYNC16(s_, d_);                                                         \
    ASYNC16(s_ + 64 * D_IN, d_ + 8192);                                      \
  } while (0)

#define RD_A(buf_, mh_, dst_) do {                                           \
    _Pragma("unroll")                                                        \
    for (int m2 = 0; m2 < 4; ++m2) {                                         \
      const char* p_ = &lds[buf_][wr][0] + ((mh_)*4 + m2) * 2048 + rowb;     \
      dst_[m2][0] = *(const bf16x8*)(p_ + koff0);                            \
      dst_[m2][1] = *(const bf16x8*)(p_ + koff1);                            \
    } } while (0)

#define RD_B(buf_, nh_, dst_) do {                                           \
    _Pragma("unroll")                                                        \
    for (int n2 = 0; n2 < 2; ++n2) {                                         \
      const char* p_ = &lds[buf_][2 + (wc >> 1)][0] + (wc & 1) * 8192 +      \
                       (nh_) * 4096 + n2 * 2048 + rowb;                      \
      dst_[n2][0] = *(const bf16x8*)(p_ + koff0);                            \
      dst_[n2][1] = *(const bf16x8*)(p_ + koff1);                            \
    } } while (0)

#define MM(afr_, bfr_, mh_, nh_) do {                                        \
    __builtin_amdgcn_s_setprio(1);                                           \
    _Pragma("unroll")                                                        \
    for (int m2 = 0; m2 < 4; ++m2) {                                         \
      _Pragma("unroll")                                                      \
      for (int n2 = 0; n2 < 2; ++n2) {                                       \
        acc[(mh_)*4 + m2][(nh_)*2 + n2] = __builtin_amdgcn_mfma_f32_16x16x32_bf16( \
            afr_[m2][0], bfr_[n2][0], acc[(mh_)*4 + m2][(nh_)*2 + n2], 0, 0, 0);   \
        acc[(mh_)*4 + m2][(nh_)*2 + n2] = __builtin_amdgcn_mfma_f32_16x16x32_bf16( \
            afr_[m2][1], bfr_[n2][1], acc[(mh_)*4 + m2][(nh_)*2 + n2], 0, 0, 0);   \
      } }                                                                    \
    __builtin_amdgcn_s_setprio(0);                                           \
  } while (0)

// One K-tile. buf_ MUST be a literal 0/1. SA_/SB_/PRE_ compile-time guards;
// VMA_/VMB_ are the two vmcnt statements (or (void)0).
#define KTILE(buf_, g_, SA_, SB_, PRE_, VMA_, VMB_) do {                     \
    /* P0: rd a_h0 (8) ; MM(a_h0, b0) */                                     \
    RD_A(buf_, 0, a);                                                        \
    if (SA_) STAGE_A((buf_) ^ 1, (g_) + 1, 0);                               \
    BAR;                                                                     \
    MM(a, b0, 0, 0);                                                         \
    BAR;                                                                     \
    /* P1: rd b1 (4) ; MM(a_h0, b1) */                                       \
    RD_B(buf_, 1, b1);                                                       \
    if (SA_) STAGE_A((buf_) ^ 1, (g_) + 1, 1);                               \
    BAR;                                                                     \
    MM(a, b1, 0, 1);                                                         \
    BAR;                                                                     \
    /* P2: rd a_h1 (8) ; MM(a_h1, b0) — last use of b0 */                    \
    RD_A(buf_, 1, a);                                                        \
    if (SB_) STAGE_B(buf_, (g_) + 2, 0);                                     \
    BAR;                                                                     \
    MM(a, b0, 1, 0);                                                         \
    BAR;                                                                     \
    /* P3: rd b0' (4, next tile) inside MFMA region ; MM(a_h1, b1) */        \
    VMA_;                                                                    \
    if (SB_) STAGE_B(buf_, (g_) + 2, 1);                                     \
    BAR;                                                                     \
    if (PRE_) RD_B((buf_) ^ 1, 0, b0);                                       \
    MM(a, b1, 1, 1);                                                         \
    VMB_;                                                                    \
    BAR;                                                                     \
  } while (0)

__global__ __launch_bounds__(512, 2) void gemm8_kernel(const unsigned short* __restrict__ xbf,
                                                       const unsigned short* __restrict__ weff,
                                                       const float* __restrict__ bias,
                                                       float* __restrict__ out) {
  __shared__ __attribute__((aligned(1024))) char lds[2][4][16384];  // 128 KiB

  const int tid  = threadIdx.x;
  const int lane = tid & 63;
  const int wid  = tid >> 6;
  const int wr   = wid >> 2;        // 0..1  (M half)
  const int wc   = wid & 3;         // 0..3  (N quarter)

  // bijective XCD swizzle: 1024 wgs, 8 XCDs -> each XCD gets 8 M-rows x 16 N-cols
  const int id  = blockIdx.x;
  const int nid = (id & 7) * 128 + (id >> 3);
  const int tn  = nid & 15;         // N tile (16)
  const int tm  = nid >> 4;         // M tile (64)

  // ds_read lane offsets (swizzled): addr = row*128 + ((kk*64 + (l>>4)*16) ^ ((l&7)<<4))
  const int rowb  = (lane & 15) * 128;
  const int kx    = (lane & 7) << 4;
  const int koff0 = (((lane >> 4) * 16) ^ kx);
  const int koff1 = ((64 + (lane >> 4) * 16) ^ kx);

  // staging lane offsets (inverse-swizzled source)
  const int sr = tid >> 3;                        // row within 64-row chunk
  const int ke = ((tid & 7) ^ (sr & 7)) * 8;      // permuted k-element offset
  const unsigned short* gA = xbf  + (size_t)(tm * BM + sr) * D_IN + ke;
  const unsigned short* gB = weff + (size_t)(tn * BN + sr) * D_IN + ke;

  f32x4 acc[8][4] = {};
  bf16x8 a[4][2], b0[2][2], b1[2][2];

  // prologue: tile 0 (A+B) -> buf0 ; B of tile 1 -> buf1  (12 loads)
  STAGE_A(0, 0, 0); STAGE_A(0, 0, 1);
  STAGE_B(0, 0, 0); STAGE_B(0, 0, 1);
  STAGE_B(1, 1, 0); STAGE_B(1, 1, 1);
  VMW(4);           // tile 0 landed; B(1)x4 stays in flight
  BAR;
  RD_B(0, 0, b0);   // preload b0 for tile 0 (compiler inserts counted lgkm wait)

  for (int g = 0; g < KT - 2; g += 2) {
    KTILE(0, g,     1, 1, 1, VMW(6), VMW(4));
    KTILE(1, g + 1, 1, 1, 1, VMW(6), VMW(4));
  }
  // tile KT-2 (buf0): stage A(KT-1) only; P3-start queue = B(KT-1)x4 + A(KT-1)x4
  KTILE(0, KT - 2, 1, 0, 1, VMW(4), VMW(0));
  // tile KT-1 (buf1): pure compute
  KTILE(1, KT - 1, 0, 0, 0, (void)0, (void)0);

  // epilogue: C/D layout col = lane&15, row = (lane>>4)*4 + j  [m89-verified]
  const int row0 = tm * BM + wr * 128 + (lane >> 4) * 4;
  const int col0 = tn * BN + wc * 64 + (lane & 15);
#pragma unroll
  for (int n = 0; n < 4; ++n) {
    const int col = col0 + n * 16;
    const float bv = bias[col];
#pragma unroll
    for (int m = 0; m < 8; ++m) {
      const int r = row0 + m * 16;
#pragma unroll
      for (int j = 0; j < 4; ++j)
        out[(size_t)(r + j) * D_OUT + col] = acc[m][n][j] + bv;
    }
  }
}

extern "C" void kernel_launch(void* const* d_in, const int* in_sizes, int n_in,
                              void* d_out, int out_size, void* d_ws, size_t ws_size,
                              hipStream_t stream) {
  const float* x      = (const float*)d_in[0];
  const int*   codes  = (const int*)d_in[1];
  const float* scales = (const float*)d_in[2];
  const float* bias   = (const float*)d_in[3];
  const float* delta  = (const float*)d_in[4];
  float* out = (float*)d_out;

  unsigned short* xbf  = (unsigned short*)d_ws;                    // 128 MiB
  unsigned short* weff = xbf + (size_t)MTOT * D_IN;                // +32 MiB

  prep_x_kernel<<<(MTOT * D_IN) / (256 * 8), 256, 0, stream>>>(x, xbf);
  prep_w_kernel<<<(D_OUT * D_IN) / (256 * 8), 256, 0, stream>>>(codes, scales, delta, weff);

  gemm8_kernel<<<(MTOT / BM) * (D_OUT / BN), 512, 0, stream>>>(xbf, weff, bias, out);
}